// Round 4
// baseline (737.904 us; speedup 1.0000x reference)
//
#include <hip/hip_runtime.h>
#include <stdint.h>
#include <stddef.h>

typedef float f32x4 __attribute__((ext_vector_type(4)));
typedef __bf16 bf16x8 __attribute__((ext_vector_type(8)));
typedef short s16x4 __attribute__((ext_vector_type(4)));

#define DEVI static __device__ __forceinline__

DEVI float bf2f(unsigned short u) {
  unsigned int x = ((unsigned int)u) << 16;
  float f;
  __builtin_memcpy(&f, &x, 4);
  return f;
}
DEVI unsigned short f2bf(float f) {
  unsigned int x;
  __builtin_memcpy(&x, &f, 4);
  unsigned int r = (x + 0x7fffu + ((x >> 16) & 1u)) >> 16;
  return (unsigned short)r;
}

DEVI void async16(const void* g, void* l) {
  __builtin_amdgcn_global_load_lds((__attribute__((address_space(1))) void*)g,
                                   (__attribute__((address_space(3))) void*)l,
                                   16, 0, 0);
}

// raw barrier: wait own LDS ops, sync, fence scheduler. vmcnt NOT drained.
#define BAR_LGKM()                                          \
  do {                                                      \
    asm volatile("s_waitcnt lgkmcnt(0)" ::: "memory");      \
    __builtin_amdgcn_s_barrier();                           \
    __builtin_amdgcn_sched_barrier(0);                      \
  } while (0)

// ---------------- fp32 -> bf16 conversion ----------------
__global__ __launch_bounds__(256) void cvt_bf16(const float* __restrict__ in,
                                                unsigned short* __restrict__ out, int n) {
  int i = (blockIdx.x * 256 + threadIdx.x) * 4;
  if (i >= n) return;
  float4 v = *(const float4*)(in + i);
  s16x4 o;
  o[0] = (short)f2bf(v.x);
  o[1] = (short)f2bf(v.y);
  o[2] = (short)f2bf(v.z);
  o[3] = (short)f2bf(v.w);
  *(s16x4*)(out + i) = o;
}

// ---------------- RoPE table: tab[t][0..63]=cos, tab[t][64..127]=sin ----------------
__global__ __launch_bounds__(256) void rope_table(float* __restrict__ tab) {
  int idx = blockIdx.x * 256 + threadIdx.x;
  if (idx >= 2048 * 64) return;
  int tt = idx >> 6, j = idx & 63;
  float inv = powf(10000.0f, -(float)j * (1.0f / 64.0f));
  float ang = (float)tt * inv;
  tab[tt * 128 + j] = cosf(ang);
  tab[tt * 128 + 64 + j] = sinf(ang);
}

// ---------------- apply RoPE in place; Q additionally pre-scaled by 1/sqrt(hd)*log2(e) ----
__global__ __launch_bounds__(256) void rope_apply(unsigned short* __restrict__ Qg,
                                                  unsigned short* __restrict__ Kg,
                                                  const float* __restrict__ tab) {
  const float S2 = 0.0883883476483184f * 1.44269504088896341f;
  int idx = blockIdx.x * 256 + threadIdx.x;  // bh*2048*64 + t*64 + j
  int j = idx & 63;
  int tt = (idx >> 6) & 2047;
  int bh = idx >> 17;
  size_t base = ((size_t)bh * 2048 + tt) * 128;
  float c = tab[tt * 128 + j], s = tab[tt * 128 + 64 + j];
  float q1 = bf2f(Qg[base + j]), q2 = bf2f(Qg[base + j + 64]);
  Qg[base + j] = f2bf((q1 * c - q2 * s) * S2);
  Qg[base + j + 64] = f2bf((q1 * s + q2 * c) * S2);
  float k1 = bf2f(Kg[base + j]), k2 = bf2f(Kg[base + j + 64]);
  Kg[base + j] = f2bf(k1 * c - k2 * s);
  Kg[base + j + 64] = f2bf(k1 * s + k2 * c);
}

// ---------------- GEMM: C[m][n] = sum_k A[m][k]*B[n][k]  (both row-major, K contiguous)
template <int EPI>
__global__ __launch_bounds__(256) void gemm_bt(const unsigned short* __restrict__ A,
                                               const unsigned short* __restrict__ B,
                                               float* __restrict__ C, int M, int N, int K,
                                               unsigned short* __restrict__ Q,
                                               unsigned short* __restrict__ Kk,
                                               unsigned short* __restrict__ VT) {
  __shared__ __attribute__((aligned(128))) unsigned short As[128 * 64];
  __shared__ __attribute__((aligned(128))) unsigned short Bs[128 * 64];
  const int t = threadIdx.x;
  const int lane = t & 63;
  const int w = t >> 6, wr = w >> 1, wc = w & 1;
  const int g = lane >> 4, lr = lane & 15;
  const int bm = blockIdx.y * 128, bn = blockIdx.x * 128;

  f32x4 acc[4][4] = {};

  const int srow = t >> 3;                 // 0..31: row within a 4KB staging chunk
  const int sslot = (t & 7) ^ (srow & 7);  // inverse-swizzled source 16B slot
  const unsigned short* aptr = A + (size_t)bm * K;
  const unsigned short* bptr = B + (size_t)bn * K;

  for (int k0 = 0; k0 < K; k0 += 64) {
    __syncthreads();
#pragma unroll
    for (int c = 0; c < 4; ++c) {
      int row = c * 32 + srow;
      async16(aptr + (size_t)row * K + k0 + sslot * 8, As + c * 2048 + t * 8);
      async16(bptr + (size_t)row * K + k0 + sslot * 8, Bs + c * 2048 + t * 8);
    }
    __syncthreads();
#pragma unroll
    for (int kk = 0; kk < 2; ++kk) {
      bf16x8 af[4], bfr[4];
#pragma unroll
      for (int i = 0; i < 4; ++i) {
        int row = wr * 64 + i * 16 + lr;
        af[i] = *(const bf16x8*)(As + row * 64 + (((kk * 4 + g) ^ (row & 7)) * 8));
        int rowb = wc * 64 + i * 16 + lr;
        bfr[i] = *(const bf16x8*)(Bs + rowb * 64 + (((kk * 4 + g) ^ (rowb & 7)) * 8));
      }
#pragma unroll
      for (int i = 0; i < 4; ++i)
#pragma unroll
        for (int j = 0; j < 4; ++j)
          acc[i][j] = __builtin_amdgcn_mfma_f32_16x16x32_bf16(af[i], bfr[j], acc[i][j], 0, 0, 0);
    }
  }

  if (EPI == 0) {
#pragma unroll
    for (int i = 0; i < 4; ++i) {
      int m0 = bm + wr * 64 + i * 16 + g * 4;
#pragma unroll
      for (int j = 0; j < 4; ++j) {
        int n = bn + wc * 64 + j * 16 + lr;
#pragma unroll
        for (int r = 0; r < 4; ++r) C[(size_t)(m0 + r) * N + n] = acc[i][j][r];
      }
    }
  } else {
    const int bi = bm >> 11;      // batch index (tile never crosses batch: 2048%128==0)
    const int tbase = bm & 2047;  // t within batch
#pragma unroll
    for (int j = 0; j < 4; ++j) {
      int e = bn + wc * 64 + j * 16 + lr;  // 0..6143 (region uniform per block)
      int region = e >> 11;
      int e2 = e & 2047;
      int h = e2 >> 7, d = e2 & 127;
      int bh = bi * 16 + h;
#pragma unroll
      for (int i = 0; i < 4; ++i) {
        int trow = tbase + wr * 64 + i * 16 + g * 4;
        if (region == 2) {
          s16x4 pk;
#pragma unroll
          for (int r = 0; r < 4; ++r) pk[r] = (short)f2bf(acc[i][j][r]);
          *(s16x4*)(VT + ((size_t)bh * 128 + d) * 2048 + trow) = pk;
        } else {
          unsigned short* dst = (region == 0) ? Q : Kk;
#pragma unroll
          for (int r = 0; r < 4; ++r)
            dst[((size_t)bh * 2048 + trow + r) * 128 + d] = f2bf(acc[i][j][r]);
        }
      }
    }
  }
}

// ---------------- flash attention ----------------
// grid (64 bh, 32 q-tiles LPT-reversed). 256 thr = 4 waves; wave w owns q rows
// [qb+16w, qb+16w+16). KV tile = 64. Reg-staged K/V with async split (loads for
// tile kt+1 issued before compute of kt; raw s_barrier, vmcnt never drained).
// P-scratch aliases Ks (3rd barrier after QK reads). exp2-domain softmax with
// defer-max (THR=8); Q pre-scaled by scale*log2e in rope_apply.
// launch_bounds(256,2): the backend's LDS-derived default (4 w/EU at 35KB LDS)
// capped VGPRs at ~128 total and spilled ~1GB/dispatch (R2: VGPR=64, R3: VGPR=80,
// both WRITE_SIZE~1.1GB). min-waves=2 raises the cap to ~256; persistent
// kreg/vreg staging needs ~150-180.
__global__ __launch_bounds__(256, 2) void flash_attn(const unsigned short* __restrict__ Qg,
                                                     const unsigned short* __restrict__ Kg,
                                                     const unsigned short* __restrict__ VTg,
                                                     unsigned short* __restrict__ Yg,
                                                     const int* __restrict__ iscausal,
                                                     const unsigned char* __restrict__ amask) {
  __shared__ __attribute__((aligned(128))) unsigned short Ks[64 * 136];  // P aliases here
  __shared__ __attribute__((aligned(128))) unsigned short Vs[128 * 72];

  const int t = threadIdx.x, lane = t & 63, w = t >> 6;
  const int g = lane >> 4, lr = lane & 15;
  const int bh = blockIdx.x, qbi = 31 - blockIdx.y, b = bh >> 4;
  const int qb = qbi * 64;
  const int causal = iscausal[0] != 0;
  const int nt = causal ? (qbi + 1) : 32;

  const unsigned short* qrow = Qg + ((size_t)bh * 2048 + qb + w * 16 + lr) * 128;
  bf16x8 qf[4];
#pragma unroll
  for (int ds = 0; ds < 4; ++ds) qf[ds] = *(const bf16x8*)(qrow + ds * 32 + g * 8);

  const int r16 = t >> 4, c16 = t & 15;
  const int r8 = t >> 3, c8 = t & 7;
  const unsigned short* Kbase = Kg + (size_t)bh * 2048 * 128;
  const unsigned short* Vbase = VTg + (size_t)bh * 128 * 2048;

  int4 kreg[4], vreg[4];
#pragma unroll
  for (int c = 0; c < 4; ++c) {
    kreg[c] = *(const int4*)(Kbase + (size_t)(c * 16 + r16) * 128 + c16 * 8);
    vreg[c] = *(const int4*)(Vbase + (size_t)(c * 32 + r8) * 2048 + c8 * 8);
  }

  f32x4 acc[8] = {};
  float mrow[4] = {-1e30f, -1e30f, -1e30f, -1e30f};
  float lrow[4] = {0.f, 0.f, 0.f, 0.f};

  for (int kt = 0; kt < nt; ++kt) {
    // barrier 1: previous tile's LDS reads (PV + P-frag) complete everywhere
    BAR_LGKM();
    // stage current tile regs -> LDS
#pragma unroll
    for (int c = 0; c < 4; ++c) *(int4*)(Ks + (c * 16 + r16) * 136 + c16 * 8) = kreg[c];
#pragma unroll
    for (int c = 0; c < 4; ++c) *(int4*)(Vs + (c * 32 + r8) * 72 + c8 * 8) = vreg[c];
    // issue next tile's global loads (stay in flight through compute)
    if (kt + 1 < nt) {
      const int kv1 = (kt + 1) * 64;
#pragma unroll
      for (int c = 0; c < 4; ++c) {
        kreg[c] = *(const int4*)(Kbase + (size_t)(kv1 + c * 16 + r16) * 128 + c16 * 8);
        vreg[c] = *(const int4*)(Vbase + (size_t)(c * 32 + r8) * 2048 + kv1 + c8 * 8);
      }
    }
    // barrier 2: staging visible
    BAR_LGKM();

    f32x4 s[4] = {};
#pragma unroll
    for (int cf = 0; cf < 4; ++cf)
#pragma unroll
      for (int ds = 0; ds < 4; ++ds) {
        bf16x8 kf = *(const bf16x8*)(Ks + (cf * 16 + lr) * 136 + ds * 32 + g * 8);
        s[cf] = __builtin_amdgcn_mfma_f32_16x16x32_bf16(qf[ds], kf, s[cf], 0, 0, 0);
      }
    // barrier 3: all QK reads of Ks done before P overwrites the alias
    BAR_LGKM();

    const int kv0 = kt * 64;
    const int q0 = qb + w * 16 + g * 4;
    if (causal) {
      if (kt == qbi) {
#pragma unroll
        for (int cf = 0; cf < 4; ++cf) {
          int kvg = kv0 + cf * 16 + lr;
#pragma unroll
          for (int r = 0; r < 4; ++r)
            if (kvg > q0 + r) s[cf][r] = -1e30f;
        }
      }
    } else {
#pragma unroll
      for (int cf = 0; cf < 4; ++cf) {
        int kvg = kv0 + cf * 16 + lr;
        if (!amask[(size_t)b * 2048 + kvg]) {
#pragma unroll
          for (int r = 0; r < 4; ++r) s[cf][r] = -1e30f;
        }
      }
    }

    f32x4 mx;
#pragma unroll
    for (int r = 0; r < 4; ++r)
      mx[r] = fmaxf(fmaxf(s[0][r], s[1][r]), fmaxf(s[2][r], s[3][r]));
#pragma unroll
    for (int off = 8; off >= 1; off >>= 1)
#pragma unroll
      for (int r = 0; r < 4; ++r) mx[r] = fmaxf(mx[r], __shfl_xor(mx[r], off));

    // defer-max: only rescale when tile max exceeds running max + 8 (log2 domain)
    bool ok = true;
#pragma unroll
    for (int r = 0; r < 4; ++r) ok = ok && (mx[r] <= mrow[r] + 8.0f);
    if (!__all(ok)) {
#pragma unroll
      for (int r = 0; r < 4; ++r) {
        float mn = fmaxf(mrow[r], mx[r]);
        float corr = exp2f(mrow[r] - mn);
        mrow[r] = mn;
        lrow[r] *= corr;
#pragma unroll
        for (int jf = 0; jf < 8; ++jf) acc[jf][r] *= corr;
      }
    }

    f32x4 rs = {0.f, 0.f, 0.f, 0.f};
#pragma unroll
    for (int cf = 0; cf < 4; ++cf)
#pragma unroll
      for (int r = 0; r < 4; ++r) {
        float p = exp2f(s[cf][r] - mrow[r]);
        s[cf][r] = p;
        rs[r] += p;
      }
#pragma unroll
    for (int off = 8; off >= 1; off >>= 1)
#pragma unroll
      for (int r = 0; r < 4; ++r) rs[r] += __shfl_xor(rs[r], off);
#pragma unroll
    for (int r = 0; r < 4; ++r) lrow[r] += rs[r];

    // P -> per-wave scratch aliased into Ks rows [w*16, w*16+16)
    unsigned short* Pw = Ks + w * 16 * 136;
#pragma unroll
    for (int cf = 0; cf < 4; ++cf)
#pragma unroll
      for (int r = 0; r < 4; ++r) Pw[(g * 4 + r) * 136 + cf * 16 + lr] = f2bf(s[cf][r]);
    asm volatile("s_waitcnt lgkmcnt(0)" ::: "memory");
    __builtin_amdgcn_sched_barrier(0);

    bf16x8 pa0 = *(const bf16x8*)(Pw + lr * 136 + g * 8);
    bf16x8 pa1 = *(const bf16x8*)(Pw + lr * 136 + 32 + g * 8);
#pragma unroll
    for (int jf = 0; jf < 8; ++jf) {
      bf16x8 v0 = *(const bf16x8*)(Vs + (jf * 16 + lr) * 72 + g * 8);
      bf16x8 v1 = *(const bf16x8*)(Vs + (jf * 16 + lr) * 72 + 32 + g * 8);
      acc[jf] = __builtin_amdgcn_mfma_f32_16x16x32_bf16(pa0, v0, acc[jf], 0, 0, 0);
      acc[jf] = __builtin_amdgcn_mfma_f32_16x16x32_bf16(pa1, v1, acc[jf], 0, 0, 0);
    }
  }

  const int h = bh & 15;
  float rl[4];
#pragma unroll
  for (int r = 0; r < 4; ++r) rl[r] = __builtin_amdgcn_rcpf(lrow[r]);
#pragma unroll
  for (int jf = 0; jf < 8; ++jf)
#pragma unroll
    for (int r = 0; r < 4; ++r) {
      int tt = qb + w * 16 + g * 4 + r;
      Yg[((size_t)b * 2048 + tt) * 2048 + h * 128 + jf * 16 + lr] = f2bf(acc[jf][r] * rl[r]);
    }
}

// ---------------- launch ----------------
extern "C" void kernel_launch(void* const* d_in, const int* in_sizes, int n_in, void* d_out,
                              int out_size, void* d_ws, size_t ws_size, hipStream_t stream) {
  const float* x = (const float*)d_in[0];
  const unsigned char* amask = (const unsigned char*)d_in[1];
  const int* iscausal = (const int*)d_in[2];
  const float* wqkv = (const float*)d_in[3];
  const float* wout = (const float*)d_in[4];
  float* out = (float*)d_out;

  const size_t MT = 8192, D = 2048, ND = 6144;
  unsigned short* xb = (unsigned short*)d_ws;
  unsigned short* wqkvb = xb + MT * D;
  unsigned short* woutb = wqkvb + ND * D;
  unsigned short* q = woutb + D * D;
  unsigned short* k = q + MT * D;
  unsigned short* vt = k + MT * D;
  unsigned short* y = vt + MT * D;
  float* tab = (float*)(y + MT * D);
  if (ws_size < (size_t)(100663296) * 2 + 2048 * 128 * 4) return;

  cvt_bf16<<<dim3(16384), dim3(256), 0, stream>>>(x, xb, (int)(MT * D));
  cvt_bf16<<<dim3(12288), dim3(256), 0, stream>>>(wqkv, wqkvb, (int)(ND * D));
  cvt_bf16<<<dim3(4096), dim3(256), 0, stream>>>(wout, woutb, (int)(D * D));
  rope_table<<<dim3(512), dim3(256), 0, stream>>>(tab);
  gemm_bt<1><<<dim3(48, 64), dim3(256), 0, stream>>>(xb, wqkvb, nullptr, 8192, 6144, 2048, q, k, vt);
  rope_apply<<<dim3(32768), dim3(256), 0, stream>>>(q, k, tab);
  flash_attn<<<dim3(64, 32), dim3(256), 0, stream>>>(q, k, vt, y, iscausal, amask);
  gemm_bt<0><<<dim3(16, 64), dim3(256), 0, stream>>>(y, woutb, out, 8192, 2048, 2048, nullptr,
                                                     nullptr, nullptr);
}

// Round 5
// 655.786 us; speedup vs baseline: 1.1252x; 1.1252x over previous
//
#include <hip/hip_runtime.h>
#include <stdint.h>
#include <stddef.h>

typedef float f32x4 __attribute__((ext_vector_type(4)));
typedef __bf16 bf16x8 __attribute__((ext_vector_type(8)));
typedef short s16x4 __attribute__((ext_vector_type(4)));

#define DEVI static __device__ __forceinline__

DEVI float bf2f(unsigned short u) {
  unsigned int x = ((unsigned int)u) << 16;
  float f;
  __builtin_memcpy(&f, &x, 4);
  return f;
}
DEVI unsigned short f2bf(float f) {
  unsigned int x;
  __builtin_memcpy(&x, &f, 4);
  unsigned int r = (x + 0x7fffu + ((x >> 16) & 1u)) >> 16;
  return (unsigned short)r;
}

DEVI void async16(const void* g, void* l) {
  __builtin_amdgcn_global_load_lds((__attribute__((address_space(1))) void*)g,
                                   (__attribute__((address_space(3))) void*)l,
                                   16, 0, 0);
}

// ---------------- fp32 -> bf16 conversion ----------------
__global__ __launch_bounds__(256) void cvt_bf16(const float* __restrict__ in,
                                                unsigned short* __restrict__ out, int n) {
  int i = (blockIdx.x * 256 + threadIdx.x) * 4;
  if (i >= n) return;
  float4 v = *(const float4*)(in + i);
  s16x4 o;
  o[0] = (short)f2bf(v.x);
  o[1] = (short)f2bf(v.y);
  o[2] = (short)f2bf(v.z);
  o[3] = (short)f2bf(v.w);
  *(s16x4*)(out + i) = o;
}

// ---------------- RoPE table: tab[t][0..63]=cos, tab[t][64..127]=sin ----------------
__global__ __launch_bounds__(256) void rope_table(float* __restrict__ tab) {
  int idx = blockIdx.x * 256 + threadIdx.x;
  if (idx >= 2048 * 64) return;
  int tt = idx >> 6, j = idx & 63;
  float inv = powf(10000.0f, -(float)j * (1.0f / 64.0f));
  float ang = (float)tt * inv;
  tab[tt * 128 + j] = cosf(ang);
  tab[tt * 128 + 64 + j] = sinf(ang);
}

// ---------------- apply RoPE in place; Q additionally pre-scaled by 1/sqrt(hd)*log2(e) ----
__global__ __launch_bounds__(256) void rope_apply(unsigned short* __restrict__ Qg,
                                                  unsigned short* __restrict__ Kg,
                                                  const float* __restrict__ tab) {
  const float S2 = 0.0883883476483184f * 1.44269504088896341f;
  int idx = blockIdx.x * 256 + threadIdx.x;  // bh*2048*64 + t*64 + j
  int j = idx & 63;
  int tt = (idx >> 6) & 2047;
  int bh = idx >> 17;
  size_t base = ((size_t)bh * 2048 + tt) * 128;
  float c = tab[tt * 128 + j], s = tab[tt * 128 + 64 + j];
  float q1 = bf2f(Qg[base + j]), q2 = bf2f(Qg[base + j + 64]);
  Qg[base + j] = f2bf((q1 * c - q2 * s) * S2);
  Qg[base + j + 64] = f2bf((q1 * s + q2 * c) * S2);
  float k1 = bf2f(Kg[base + j]), k2 = bf2f(Kg[base + j + 64]);
  Kg[base + j] = f2bf(k1 * c - k2 * s);
  Kg[base + j + 64] = f2bf(k1 * s + k2 * c);
}

// ---------------- GEMM: C[m][n] = sum_k A[m][k]*B[n][k]  (both row-major, K contiguous)
template <int EPI>
__global__ __launch_bounds__(256) void gemm_bt(const unsigned short* __restrict__ A,
                                               const unsigned short* __restrict__ B,
                                               float* __restrict__ C, int M, int N, int K,
                                               unsigned short* __restrict__ Q,
                                               unsigned short* __restrict__ Kk,
                                               unsigned short* __restrict__ VT) {
  __shared__ __attribute__((aligned(128))) unsigned short As[128 * 64];
  __shared__ __attribute__((aligned(128))) unsigned short Bs[128 * 64];
  const int t = threadIdx.x;
  const int lane = t & 63;
  const int w = t >> 6, wr = w >> 1, wc = w & 1;
  const int g = lane >> 4, lr = lane & 15;
  const int bm = blockIdx.y * 128, bn = blockIdx.x * 128;

  f32x4 acc[4][4] = {};

  const int srow = t >> 3;                 // 0..31: row within a 4KB staging chunk
  const int sslot = (t & 7) ^ (srow & 7);  // inverse-swizzled source 16B slot
  const unsigned short* aptr = A + (size_t)bm * K;
  const unsigned short* bptr = B + (size_t)bn * K;

  for (int k0 = 0; k0 < K; k0 += 64) {
    __syncthreads();
#pragma unroll
    for (int c = 0; c < 4; ++c) {
      int row = c * 32 + srow;
      async16(aptr + (size_t)row * K + k0 + sslot * 8, As + c * 2048 + t * 8);
      async16(bptr + (size_t)row * K + k0 + sslot * 8, Bs + c * 2048 + t * 8);
    }
    __syncthreads();
#pragma unroll
    for (int kk = 0; kk < 2; ++kk) {
      bf16x8 af[4], bfr[4];
#pragma unroll
      for (int i = 0; i < 4; ++i) {
        int row = wr * 64 + i * 16 + lr;
        af[i] = *(const bf16x8*)(As + row * 64 + (((kk * 4 + g) ^ (row & 7)) * 8));
        int rowb = wc * 64 + i * 16 + lr;
        bfr[i] = *(const bf16x8*)(Bs + rowb * 64 + (((kk * 4 + g) ^ (rowb & 7)) * 8));
      }
#pragma unroll
      for (int i = 0; i < 4; ++i)
#pragma unroll
        for (int j = 0; j < 4; ++j)
          acc[i][j] = __builtin_amdgcn_mfma_f32_16x16x32_bf16(af[i], bfr[j], acc[i][j], 0, 0, 0);
    }
  }

  if (EPI == 0) {
#pragma unroll
    for (int i = 0; i < 4; ++i) {
      int m0 = bm + wr * 64 + i * 16 + g * 4;
#pragma unroll
      for (int j = 0; j < 4; ++j) {
        int n = bn + wc * 64 + j * 16 + lr;
#pragma unroll
        for (int r = 0; r < 4; ++r) C[(size_t)(m0 + r) * N + n] = acc[i][j][r];
      }
    }
  } else {
    const int bi = bm >> 11;      // batch index (tile never crosses batch: 2048%128==0)
    const int tbase = bm & 2047;  // t within batch
#pragma unroll
    for (int j = 0; j < 4; ++j) {
      int e = bn + wc * 64 + j * 16 + lr;  // 0..6143 (region uniform per block)
      int region = e >> 11;
      int e2 = e & 2047;
      int h = e2 >> 7, d = e2 & 127;
      int bh = bi * 16 + h;
#pragma unroll
      for (int i = 0; i < 4; ++i) {
        int trow = tbase + wr * 64 + i * 16 + g * 4;
        if (region == 2) {
          s16x4 pk;
#pragma unroll
          for (int r = 0; r < 4; ++r) pk[r] = (short)f2bf(acc[i][j][r]);
          *(s16x4*)(VT + ((size_t)bh * 128 + d) * 2048 + trow) = pk;
        } else {
          unsigned short* dst = (region == 0) ? Q : Kk;
#pragma unroll
          for (int r = 0; r < 4; ++r)
            dst[((size_t)bh * 2048 + trow + r) * 128 + d] = f2bf(acc[i][j][r]);
        }
      }
    }
  }
}

// ---------------- flash attention ----------------
// 1-D grid 2048. XCD-affinity swizzle: xcd=id&7 (dispatch round-robins XCDs),
// bh = xcd*8 + (j>>5), qbi = 31-(j&31) (LPT heavy-first). All 32 q-tiles of a
// bh land on ONE XCD -> its L2 fetches that bh's 1MB K/V once.
// 256 thr = 4 waves; wave w owns q rows [qb+16w,+16). KV tile 64.
// R1-style IMMEDIATE staging (transient int4, global->LDS in one step):
// persistent cross-tile prefetch regs caused ~1.1GB/dispatch scratch spill in
// R2-R4 regardless of launch_bounds (VGPR_Count 60-84, WRITE_SIZE ~1.1e6 KB).
// P-scratch aliases Ks (3rd barrier). exp2-domain softmax, defer-max THR=8,
// Q pre-scaled by scale*log2e in rope_apply.
__global__ __launch_bounds__(256) void flash_attn(const unsigned short* __restrict__ Qg,
                                                  const unsigned short* __restrict__ Kg,
                                                  const unsigned short* __restrict__ VTg,
                                                  unsigned short* __restrict__ Yg,
                                                  const int* __restrict__ iscausal,
                                                  const unsigned char* __restrict__ amask) {
  __shared__ __attribute__((aligned(128))) unsigned short Ks[64 * 136];  // P aliases here
  __shared__ __attribute__((aligned(128))) unsigned short Vs[128 * 72];

  const int t = threadIdx.x, lane = t & 63, w = t >> 6;
  const int g = lane >> 4, lr = lane & 15;
  const int id = blockIdx.x;
  const int xcd = id & 7, j5 = id >> 3;
  const int bh = xcd * 8 + (j5 >> 5);
  const int qbi = 31 - (j5 & 31);
  const int b = bh >> 4;
  const int qb = qbi * 64;
  const int causal = iscausal[0] != 0;
  const int nt = causal ? (qbi + 1) : 32;

  const unsigned short* qrow = Qg + ((size_t)bh * 2048 + qb + w * 16 + lr) * 128;
  bf16x8 qf[4];
#pragma unroll
  for (int ds = 0; ds < 4; ++ds) qf[ds] = *(const bf16x8*)(qrow + ds * 32 + g * 8);

  const int r16 = t >> 4, c16 = t & 15;
  const int r8 = t >> 3, c8 = t & 7;
  const unsigned short* Kbase = Kg + (size_t)bh * 2048 * 128;
  const unsigned short* Vbase = VTg + (size_t)bh * 128 * 2048;

  f32x4 acc[8] = {};
  float mrow[4] = {-1e30f, -1e30f, -1e30f, -1e30f};
  float lrow[4] = {0.f, 0.f, 0.f, 0.f};

  for (int kt = 0; kt < nt; ++kt) {
    const int kv0 = kt * 64;
    __syncthreads();
    // immediate staging: transient registers, short live ranges (no spill)
#pragma unroll
    for (int c = 0; c < 4; ++c) {
      int4 v = *(const int4*)(Kbase + (size_t)(kv0 + c * 16 + r16) * 128 + c16 * 8);
      *(int4*)(Ks + (c * 16 + r16) * 136 + c16 * 8) = v;
    }
#pragma unroll
    for (int c = 0; c < 4; ++c) {
      int4 v = *(const int4*)(Vbase + (size_t)(c * 32 + r8) * 2048 + kv0 + c8 * 8);
      *(int4*)(Vs + (c * 32 + r8) * 72 + c8 * 8) = v;
    }
    __syncthreads();

    f32x4 s[4] = {};
#pragma unroll
    for (int cf = 0; cf < 4; ++cf)
#pragma unroll
      for (int ds = 0; ds < 4; ++ds) {
        bf16x8 kf = *(const bf16x8*)(Ks + (cf * 16 + lr) * 136 + ds * 32 + g * 8);
        s[cf] = __builtin_amdgcn_mfma_f32_16x16x32_bf16(qf[ds], kf, s[cf], 0, 0, 0);
      }
    // barrier 3: all QK reads of Ks done before P overwrites the alias
    __syncthreads();

    const int q0 = qb + w * 16 + g * 4;
    if (causal) {
      if (kt == qbi) {
#pragma unroll
        for (int cf = 0; cf < 4; ++cf) {
          int kvg = kv0 + cf * 16 + lr;
#pragma unroll
          for (int r = 0; r < 4; ++r)
            if (kvg > q0 + r) s[cf][r] = -1e30f;
        }
      }
    } else {
#pragma unroll
      for (int cf = 0; cf < 4; ++cf) {
        int kvg = kv0 + cf * 16 + lr;
        if (!amask[(size_t)b * 2048 + kvg]) {
#pragma unroll
          for (int r = 0; r < 4; ++r) s[cf][r] = -1e30f;
        }
      }
    }

    f32x4 mx;
#pragma unroll
    for (int r = 0; r < 4; ++r)
      mx[r] = fmaxf(fmaxf(s[0][r], s[1][r]), fmaxf(s[2][r], s[3][r]));
#pragma unroll
    for (int off = 8; off >= 1; off >>= 1)
#pragma unroll
      for (int r = 0; r < 4; ++r) mx[r] = fmaxf(mx[r], __shfl_xor(mx[r], off));

    // defer-max: only rescale when tile max exceeds running max + 8 (log2 domain)
    bool ok = true;
#pragma unroll
    for (int r = 0; r < 4; ++r) ok = ok && (mx[r] <= mrow[r] + 8.0f);
    if (!__all(ok)) {
#pragma unroll
      for (int r = 0; r < 4; ++r) {
        float mn = fmaxf(mrow[r], mx[r]);
        float corr = exp2f(mrow[r] - mn);
        mrow[r] = mn;
        lrow[r] *= corr;
#pragma unroll
        for (int jf = 0; jf < 8; ++jf) acc[jf][r] *= corr;
      }
    }

    f32x4 rs = {0.f, 0.f, 0.f, 0.f};
#pragma unroll
    for (int cf = 0; cf < 4; ++cf)
#pragma unroll
      for (int r = 0; r < 4; ++r) {
        float p = exp2f(s[cf][r] - mrow[r]);
        s[cf][r] = p;
        rs[r] += p;
      }
#pragma unroll
    for (int off = 8; off >= 1; off >>= 1)
#pragma unroll
      for (int r = 0; r < 4; ++r) rs[r] += __shfl_xor(rs[r], off);
#pragma unroll
    for (int r = 0; r < 4; ++r) lrow[r] += rs[r];

    // P -> per-wave scratch aliased into Ks rows [w*16, w*16+16)
    unsigned short* Pw = Ks + w * 16 * 136;
#pragma unroll
    for (int cf = 0; cf < 4; ++cf)
#pragma unroll
      for (int r = 0; r < 4; ++r) Pw[(g * 4 + r) * 136 + cf * 16 + lr] = f2bf(s[cf][r]);
    asm volatile("s_waitcnt lgkmcnt(0)" ::: "memory");
    __builtin_amdgcn_sched_barrier(0);

    bf16x8 pa0 = *(const bf16x8*)(Pw + lr * 136 + g * 8);
    bf16x8 pa1 = *(const bf16x8*)(Pw + lr * 136 + 32 + g * 8);
#pragma unroll
    for (int jf = 0; jf < 8; ++jf) {
      bf16x8 v0 = *(const bf16x8*)(Vs + (jf * 16 + lr) * 72 + g * 8);
      bf16x8 v1 = *(const bf16x8*)(Vs + (jf * 16 + lr) * 72 + 32 + g * 8);
      acc[jf] = __builtin_amdgcn_mfma_f32_16x16x32_bf16(pa0, v0, acc[jf], 0, 0, 0);
      acc[jf] = __builtin_amdgcn_mfma_f32_16x16x32_bf16(pa1, v1, acc[jf], 0, 0, 0);
    }
  }

  const int h = bh & 15;
  float rl[4];
#pragma unroll
  for (int r = 0; r < 4; ++r) rl[r] = __builtin_amdgcn_rcpf(lrow[r]);
#pragma unroll
  for (int jf = 0; jf < 8; ++jf)
#pragma unroll
    for (int r = 0; r < 4; ++r) {
      int tt = qb + w * 16 + g * 4 + r;
      Yg[((size_t)b * 2048 + tt) * 2048 + h * 128 + jf * 16 + lr] = f2bf(acc[jf][r] * rl[r]);
    }
}

// ---------------- launch ----------------
extern "C" void kernel_launch(void* const* d_in, const int* in_sizes, int n_in, void* d_out,
                              int out_size, void* d_ws, size_t ws_size, hipStream_t stream) {
  const float* x = (const float*)d_in[0];
  const unsigned char* amask = (const unsigned char*)d_in[1];
  const int* iscausal = (const int*)d_in[2];
  const float* wqkv = (const float*)d_in[3];
  const float* wout = (const float*)d_in[4];
  float* out = (float*)d_out;

  const size_t MT = 8192, D = 2048, ND = 6144;
  unsigned short* xb = (unsigned short*)d_ws;
  unsigned short* wqkvb = xb + MT * D;
  unsigned short* woutb = wqkvb + ND * D;
  unsigned short* q = woutb + D * D;
  unsigned short* k = q + MT * D;
  unsigned short* vt = k + MT * D;
  unsigned short* y = vt + MT * D;
  float* tab = (float*)(y + MT * D);
  if (ws_size < (size_t)(100663296) * 2 + 2048 * 128 * 4) return;

  cvt_bf16<<<dim3(16384), dim3(256), 0, stream>>>(x, xb, (int)(MT * D));
  cvt_bf16<<<dim3(12288), dim3(256), 0, stream>>>(wqkv, wqkvb, (int)(ND * D));
  cvt_bf16<<<dim3(4096), dim3(256), 0, stream>>>(wout, woutb, (int)(D * D));
  rope_table<<<dim3(512), dim3(256), 0, stream>>>(tab);
  gemm_bt<1><<<dim3(48, 64), dim3(256), 0, stream>>>(xb, wqkvb, nullptr, 8192, 6144, 2048, q, k, vt);
  rope_apply<<<dim3(32768), dim3(256), 0, stream>>>(q, k, tab);
  flash_attn<<<dim3(2048), dim3(256), 0, stream>>>(q, k, vt, y, iscausal, amask);
  gemm_bt<0><<<dim3(16, 64), dim3(256), 0, stream>>>(y, woutb, out, 8192, 2048, 2048, nullptr,
                                                     nullptr, nullptr);
}

// Round 6
// 597.424 us; speedup vs baseline: 1.2351x; 1.0977x over previous
//
#include <hip/hip_runtime.h>
#include <stdint.h>
#include <stddef.h>

typedef float f32x4 __attribute__((ext_vector_type(4)));
typedef __bf16 bf16x8 __attribute__((ext_vector_type(8)));
typedef short s16x4 __attribute__((ext_vector_type(4)));

#define DEVI static __device__ __forceinline__

DEVI float bf2f(unsigned short u) {
  unsigned int x = ((unsigned int)u) << 16;
  float f;
  __builtin_memcpy(&f, &x, 4);
  return f;
}
DEVI unsigned short f2bf(float f) {
  unsigned int x;
  __builtin_memcpy(&x, &f, 4);
  unsigned int r = (x + 0x7fffu + ((x >> 16) & 1u)) >> 16;
  return (unsigned short)r;
}

DEVI void async16(const void* g, void* l) {
  __builtin_amdgcn_global_load_lds((__attribute__((address_space(1))) void*)g,
                                   (__attribute__((address_space(3))) void*)l,
                                   16, 0, 0);
}

// raw barrier with own-LDS-ops drain; vmcnt NOT touched.
#define BAR_LGKM()                                          \
  do {                                                      \
    asm volatile("s_waitcnt lgkmcnt(0)" ::: "memory");      \
    __builtin_amdgcn_s_barrier();                           \
    __builtin_amdgcn_sched_barrier(0);                      \
  } while (0)

// counted-vmcnt barrier: N loads may stay in flight (T4).
#define BAR_VM(N)                                               \
  do {                                                          \
    asm volatile("s_waitcnt vmcnt(" #N ")" ::: "memory");       \
    __builtin_amdgcn_s_barrier();                               \
    __builtin_amdgcn_sched_barrier(0);                          \
  } while (0)

// ---------------- fp32 -> bf16 conversion ----------------
__global__ __launch_bounds__(256) void cvt_bf16(const float* __restrict__ in,
                                                unsigned short* __restrict__ out, int n) {
  int i = (blockIdx.x * 256 + threadIdx.x) * 4;
  if (i >= n) return;
  float4 v = *(const float4*)(in + i);
  s16x4 o;
  o[0] = (short)f2bf(v.x);
  o[1] = (short)f2bf(v.y);
  o[2] = (short)f2bf(v.z);
  o[3] = (short)f2bf(v.w);
  *(s16x4*)(out + i) = o;
}

// ---------------- RoPE table: tab[t][0..63]=cos, tab[t][64..127]=sin ----------------
__global__ __launch_bounds__(256) void rope_table(float* __restrict__ tab) {
  int idx = blockIdx.x * 256 + threadIdx.x;
  if (idx >= 2048 * 64) return;
  int tt = idx >> 6, j = idx & 63;
  float inv = powf(10000.0f, -(float)j * (1.0f / 64.0f));
  float ang = (float)tt * inv;
  tab[tt * 128 + j] = cosf(ang);
  tab[tt * 128 + 64 + j] = sinf(ang);
}

// ---------------- apply RoPE in place; Q additionally pre-scaled by 1/sqrt(hd)*log2(e) ----
__global__ __launch_bounds__(256) void rope_apply(unsigned short* __restrict__ Qg,
                                                  unsigned short* __restrict__ Kg,
                                                  const float* __restrict__ tab) {
  const float S2 = 0.0883883476483184f * 1.44269504088896341f;
  int idx = blockIdx.x * 256 + threadIdx.x;  // bh*2048*64 + t*64 + j
  int j = idx & 63;
  int tt = (idx >> 6) & 2047;
  int bh = idx >> 17;
  size_t base = ((size_t)bh * 2048 + tt) * 128;
  float c = tab[tt * 128 + j], s = tab[tt * 128 + 64 + j];
  float q1 = bf2f(Qg[base + j]), q2 = bf2f(Qg[base + j + 64]);
  Qg[base + j] = f2bf((q1 * c - q2 * s) * S2);
  Qg[base + j + 64] = f2bf((q1 * s + q2 * c) * S2);
  float k1 = bf2f(Kg[base + j]), k2 = bf2f(Kg[base + j + 64]);
  Kg[base + j] = f2bf(k1 * c - k2 * s);
  Kg[base + j + 64] = f2bf(k1 * s + k2 * c);
}

// ---------------- GEMM: C[m][n] = sum_k A[m][k]*B[n][k]  (both row-major, K contiguous)
template <int EPI>
__global__ __launch_bounds__(256) void gemm_bt(const unsigned short* __restrict__ A,
                                               const unsigned short* __restrict__ B,
                                               float* __restrict__ C, int M, int N, int K,
                                               unsigned short* __restrict__ Q,
                                               unsigned short* __restrict__ Kk,
                                               unsigned short* __restrict__ VT) {
  __shared__ __attribute__((aligned(128))) unsigned short As[128 * 64];
  __shared__ __attribute__((aligned(128))) unsigned short Bs[128 * 64];
  const int t = threadIdx.x;
  const int lane = t & 63;
  const int w = t >> 6, wr = w >> 1, wc = w & 1;
  const int g = lane >> 4, lr = lane & 15;
  const int bm = blockIdx.y * 128, bn = blockIdx.x * 128;

  f32x4 acc[4][4] = {};

  const int srow = t >> 3;                 // 0..31: row within a 4KB staging chunk
  const int sslot = (t & 7) ^ (srow & 7);  // inverse-swizzled source 16B slot
  const unsigned short* aptr = A + (size_t)bm * K;
  const unsigned short* bptr = B + (size_t)bn * K;

  for (int k0 = 0; k0 < K; k0 += 64) {
    __syncthreads();
#pragma unroll
    for (int c = 0; c < 4; ++c) {
      int row = c * 32 + srow;
      async16(aptr + (size_t)row * K + k0 + sslot * 8, As + c * 2048 + t * 8);
      async16(bptr + (size_t)row * K + k0 + sslot * 8, Bs + c * 2048 + t * 8);
    }
    __syncthreads();
#pragma unroll
    for (int kk = 0; kk < 2; ++kk) {
      bf16x8 af[4], bfr[4];
#pragma unroll
      for (int i = 0; i < 4; ++i) {
        int row = wr * 64 + i * 16 + lr;
        af[i] = *(const bf16x8*)(As + row * 64 + (((kk * 4 + g) ^ (row & 7)) * 8));
        int rowb = wc * 64 + i * 16 + lr;
        bfr[i] = *(const bf16x8*)(Bs + rowb * 64 + (((kk * 4 + g) ^ (rowb & 7)) * 8));
      }
#pragma unroll
      for (int i = 0; i < 4; ++i)
#pragma unroll
        for (int j = 0; j < 4; ++j)
          acc[i][j] = __builtin_amdgcn_mfma_f32_16x16x32_bf16(af[i], bfr[j], acc[i][j], 0, 0, 0);
    }
  }

  if (EPI == 0) {
#pragma unroll
    for (int i = 0; i < 4; ++i) {
      int m0 = bm + wr * 64 + i * 16 + g * 4;
#pragma unroll
      for (int j = 0; j < 4; ++j) {
        int n = bn + wc * 64 + j * 16 + lr;
#pragma unroll
        for (int r = 0; r < 4; ++r) C[(size_t)(m0 + r) * N + n] = acc[i][j][r];
      }
    }
  } else {
    const int bi = bm >> 11;      // batch index (tile never crosses batch: 2048%128==0)
    const int tbase = bm & 2047;  // t within batch
#pragma unroll
    for (int j = 0; j < 4; ++j) {
      int e = bn + wc * 64 + j * 16 + lr;  // 0..6143 (region uniform per block)
      int region = e >> 11;
      int e2 = e & 2047;
      int h = e2 >> 7, d = e2 & 127;
      int bh = bi * 16 + h;
#pragma unroll
      for (int i = 0; i < 4; ++i) {
        int trow = tbase + wr * 64 + i * 16 + g * 4;
        if (region == 2) {
          s16x4 pk;
#pragma unroll
          for (int r = 0; r < 4; ++r) pk[r] = (short)f2bf(acc[i][j][r]);
          *(s16x4*)(VT + ((size_t)bh * 128 + d) * 2048 + trow) = pk;
        } else {
          unsigned short* dst = (region == 0) ? Q : Kk;
#pragma unroll
          for (int r = 0; r < 4; ++r)
            dst[((size_t)bh * 2048 + trow + r) * 128 + d] = f2bf(acc[i][j][r]);
        }
      }
    }
  }
}

// ---------------- flash attention ----------------
// 1-D grid 2048, XCD-affinity swizzle (R5: FETCH 49MB). 256 thr = 4 waves;
// wave w owns q rows [qb+16w,+16). KV tile 64.
// NEW (R6): double-buffered K/V staged via global_load_lds (zero staging VGPRs
// -> no spill), XOR-swizzled SOURCE + swizzled ds_reads (rule #21), counted
// vmcnt(8) barrier so next tile's 8 loads stay in flight across the whole
// compute phase (T3+T4 2-phase recipe). P in its own padded buffer.
// LDS: K 2x16K + V 2x16K + P 9.2K = 74.7KB -> 2 blocks/CU.
__global__ __launch_bounds__(256) void flash_attn(const unsigned short* __restrict__ Qg,
                                                  const unsigned short* __restrict__ Kg,
                                                  const unsigned short* __restrict__ VTg,
                                                  unsigned short* __restrict__ Yg,
                                                  const int* __restrict__ iscausal,
                                                  const unsigned char* __restrict__ amask) {
  __shared__ __attribute__((aligned(128))) unsigned short Ks[2][64 * 128];
  __shared__ __attribute__((aligned(128))) unsigned short Vs[2][128 * 64];
  __shared__ __attribute__((aligned(128))) unsigned short Ps[4][16 * 72];

  const int t = threadIdx.x, lane = t & 63, w = t >> 6;
  const int g = lane >> 4, lr = lane & 15;
  const int id = blockIdx.x;
  const int xcd = id & 7, j5 = id >> 3;
  const int bh = xcd * 8 + (j5 >> 5);
  const int qbi = 31 - (j5 & 31);
  const int b = bh >> 4;
  const int qb = qbi * 64;
  const int causal = iscausal[0] != 0;
  const int nt = causal ? (qbi + 1) : 32;

  const unsigned short* qrow = Qg + ((size_t)bh * 2048 + qb + w * 16 + lr) * 128;
  bf16x8 qf[4];
#pragma unroll
  for (int ds = 0; ds < 4; ++ds) qf[ds] = *(const bf16x8*)(qrow + ds * 32 + g * 8);

  const unsigned short* Kbase = Kg + (size_t)bh * 2048 * 128;
  const unsigned short* Vbase = VTg + (size_t)bh * 128 * 2048;

  // staging geometry (per thread): K row rK=t>>4 (16B slot t&15), V row rV=t>>3
  const int rK = t >> 4, sK = ((t & 15) ^ rK);        // source slot, XOR-swizzled
  const int rV = t >> 3, sV = ((t & 7) ^ ((t >> 3) & 7));

#define STAGE(KT, P)                                                                    \
  do {                                                                                  \
    const int _kv = (KT) * 64;                                                          \
    _Pragma("unroll") for (int c = 0; c < 4; ++c)                                       \
        async16(Kbase + (size_t)(_kv + c * 16 + rK) * 128 + sK * 8,                     \
                &Ks[P][c * 2048 + t * 8]);                                              \
    _Pragma("unroll") for (int c = 0; c < 4; ++c)                                       \
        async16(Vbase + (size_t)(c * 32 + rV) * 2048 + _kv + sV * 8,                    \
                &Vs[P][c * 2048 + t * 8]);                                              \
  } while (0)

  f32x4 acc[8] = {};
  float mrow[4] = {-1e30f, -1e30f, -1e30f, -1e30f};
  float lrow[4] = {0.f, 0.f, 0.f, 0.f};

  STAGE(0, 0);  // prologue: 8 loads in flight

  for (int kt = 0; kt < nt; ++kt) {
    const int p = kt & 1;
    const int kv0 = kt * 64;
    // issue next tile (buf p^1 free since end-of-iter barrier of kt-1), then
    // wait ONLY for tile kt's 8 loads; kt+1's stay in flight through compute.
    if (kt + 1 < nt) {
      STAGE(kt + 1, p ^ 1);
      BAR_VM(8);
    } else {
      BAR_VM(0);
    }

    f32x4 s[4] = {};
    __builtin_amdgcn_s_setprio(1);
#pragma unroll
    for (int cf = 0; cf < 4; ++cf)
#pragma unroll
      for (int ds = 0; ds < 4; ++ds) {
        bf16x8 kf = *(const bf16x8*)(&Ks[p][(cf * 16 + lr) * 128 + (((ds * 4 + g) ^ lr) * 8)]);
        s[cf] = __builtin_amdgcn_mfma_f32_16x16x32_bf16(qf[ds], kf, s[cf], 0, 0, 0);
      }
    __builtin_amdgcn_s_setprio(0);

    const int q0 = qb + w * 16 + g * 4;
    if (causal) {
      if (kt == qbi) {
#pragma unroll
        for (int cf = 0; cf < 4; ++cf) {
          int kvg = kv0 + cf * 16 + lr;
#pragma unroll
          for (int r = 0; r < 4; ++r)
            if (kvg > q0 + r) s[cf][r] = -1e30f;
        }
      }
    } else {
#pragma unroll
      for (int cf = 0; cf < 4; ++cf) {
        int kvg = kv0 + cf * 16 + lr;
        if (!amask[(size_t)b * 2048 + kvg]) {
#pragma unroll
          for (int r = 0; r < 4; ++r) s[cf][r] = -1e30f;
        }
      }
    }

    f32x4 mx;
#pragma unroll
    for (int r = 0; r < 4; ++r)
      mx[r] = fmaxf(fmaxf(s[0][r], s[1][r]), fmaxf(s[2][r], s[3][r]));
#pragma unroll
    for (int off = 8; off >= 1; off >>= 1)
#pragma unroll
      for (int r = 0; r < 4; ++r) mx[r] = fmaxf(mx[r], __shfl_xor(mx[r], off));

    // defer-max: only rescale when tile max exceeds running max + 8 (log2 domain)
    bool ok = true;
#pragma unroll
    for (int r = 0; r < 4; ++r) ok = ok && (mx[r] <= mrow[r] + 8.0f);
    if (!__all(ok)) {
#pragma unroll
      for (int r = 0; r < 4; ++r) {
        float mn = fmaxf(mrow[r], mx[r]);
        float corr = exp2f(mrow[r] - mn);
        mrow[r] = mn;
        lrow[r] *= corr;
#pragma unroll
        for (int jf = 0; jf < 8; ++jf) acc[jf][r] *= corr;
      }
    }

    f32x4 rs = {0.f, 0.f, 0.f, 0.f};
#pragma unroll
    for (int cf = 0; cf < 4; ++cf)
#pragma unroll
      for (int r = 0; r < 4; ++r) {
        float p2 = exp2f(s[cf][r] - mrow[r]);
        s[cf][r] = p2;
        rs[r] += p2;
      }
#pragma unroll
    for (int off = 8; off >= 1; off >>= 1)
#pragma unroll
      for (int r = 0; r < 4; ++r) rs[r] += __shfl_xor(rs[r], off);
#pragma unroll
    for (int r = 0; r < 4; ++r) lrow[r] += rs[r];

    // P -> per-wave padded scratch (wave-private: only intra-wave ordering needed)
    unsigned short* Pw = &Ps[w][0];
#pragma unroll
    for (int cf = 0; cf < 4; ++cf)
#pragma unroll
      for (int r = 0; r < 4; ++r) Pw[(g * 4 + r) * 72 + cf * 16 + lr] = f2bf(s[cf][r]);
    asm volatile("s_waitcnt lgkmcnt(0)" ::: "memory");
    __builtin_amdgcn_sched_barrier(0);

    bf16x8 pa0 = *(const bf16x8*)(Pw + lr * 72 + g * 8);
    bf16x8 pa1 = *(const bf16x8*)(Pw + lr * 72 + 32 + g * 8);
    __builtin_amdgcn_s_setprio(1);
#pragma unroll
    for (int jf = 0; jf < 8; ++jf) {
      bf16x8 v0 = *(const bf16x8*)(&Vs[p][(jf * 16 + lr) * 64 + ((g ^ (lr & 7)) * 8)]);
      bf16x8 v1 = *(const bf16x8*)(&Vs[p][(jf * 16 + lr) * 64 + (((4 + g) ^ (lr & 7)) * 8)]);
      acc[jf] = __builtin_amdgcn_mfma_f32_16x16x32_bf16(pa0, v0, acc[jf], 0, 0, 0);
      acc[jf] = __builtin_amdgcn_mfma_f32_16x16x32_bf16(pa1, v1, acc[jf], 0, 0, 0);
    }
    __builtin_amdgcn_s_setprio(0);

    // end: all this tile's LDS reads done everywhere -> buf[p] may be restaged
    BAR_LGKM();
  }
#undef STAGE

  const int h = bh & 15;
  float rl[4];
#pragma unroll
  for (int r = 0; r < 4; ++r) rl[r] = __builtin_amdgcn_rcpf(lrow[r]);
#pragma unroll
  for (int jf = 0; jf < 8; ++jf)
#pragma unroll
    for (int r = 0; r < 4; ++r) {
      int tt = qb + w * 16 + g * 4 + r;
      Yg[((size_t)b * 2048 + tt) * 2048 + h * 128 + jf * 16 + lr] = f2bf(acc[jf][r] * rl[r]);
    }
}

// ---------------- launch ----------------
extern "C" void kernel_launch(void* const* d_in, const int* in_sizes, int n_in, void* d_out,
                              int out_size, void* d_ws, size_t ws_size, hipStream_t stream) {
  const float* x = (const float*)d_in[0];
  const unsigned char* amask = (const unsigned char*)d_in[1];
  const int* iscausal = (const int*)d_in[2];
  const float* wqkv = (const float*)d_in[3];
  const float* wout = (const float*)d_in[4];
  float* out = (float*)d_out;

  const size_t MT = 8192, D = 2048, ND = 6144;
  unsigned short* xb = (unsigned short*)d_ws;
  unsigned short* wqkvb = xb + MT * D;
  unsigned short* woutb = wqkvb + ND * D;
  unsigned short* q = woutb + D * D;
  unsigned short* k = q + MT * D;
  unsigned short* vt = k + MT * D;
  unsigned short* y = vt + MT * D;
  float* tab = (float*)(y + MT * D);
  if (ws_size < (size_t)(100663296) * 2 + 2048 * 128 * 4) return;

  cvt_bf16<<<dim3(16384), dim3(256), 0, stream>>>(x, xb, (int)(MT * D));
  cvt_bf16<<<dim3(12288), dim3(256), 0, stream>>>(wqkv, wqkvb, (int)(ND * D));
  cvt_bf16<<<dim3(4096), dim3(256), 0, stream>>>(wout, woutb, (int)(D * D));
  rope_table<<<dim3(512), dim3(256), 0, stream>>>(tab);
  gemm_bt<1><<<dim3(48, 64), dim3(256), 0, stream>>>(xb, wqkvb, nullptr, 8192, 6144, 2048, q, k, vt);
  rope_apply<<<dim3(32768), dim3(256), 0, stream>>>(q, k, tab);
  flash_attn<<<dim3(2048), dim3(256), 0, stream>>>(q, k, vt, y, iscausal, amask);
  gemm_bt<0><<<dim3(16, 64), dim3(256), 0, stream>>>(y, woutb, out, 8192, 2048, 2048, nullptr,
                                                     nullptr, nullptr);
}